// Round 1
// baseline (285.321 us; speedup 1.0000x reference)
//
#include <hip/hip_runtime.h>
#include <hip/hip_bf16.h>

// LSTM: SEQ=64, IN=100000, H=50 (4H=200 gates)
// inputs: x[64,1,100000] f32, Wi[100000,200] f32, bi[200], Wh[50,200], bh[200]
// out: h_final[50] f32
//
// K1: split-K GEMM C[64,200] = x @ Wi, partials per block (coalesced [b][g][s] layout)
// K2: reduce partials over 512 blocks + bi + bh -> gates[s][g]
// K3: 64-step recurrence, single block

#define K_DIM 100000
#define NG 200
#define NS 64
#define TK 64
#define XS_STRIDE 65   // pad: (k*65 + lane) % 32 -> 2-way aliasing only (free)
#define NBLK 512       // split-K blocks
#define CELLS (NS * NG)  // 12800

__global__ __launch_bounds__(512) void k1_gemm_partial(
    const float* __restrict__ x, const float* __restrict__ Wi,
    float* __restrict__ partial)
{
    __shared__ float xs[TK * XS_STRIDE];
    const int tid  = threadIdx.x;
    const int lane = tid & 63;          // = s row
    const int wave = tid >> 6;          // 0..7, owns g range [25w, 25w+25)
    const int gbase = __builtin_amdgcn_readfirstlane(wave * 25);

    float acc[25];
#pragma unroll
    for (int j = 0; j < 25; ++j) acc[j] = 0.f;

    for (int kt = blockIdx.x * TK; kt < K_DIM; kt += gridDim.x * TK) {
        __syncthreads();   // protect xs from previous tile's readers
        // stage x[s][kt..kt+63] -> xs[k_local][s]; 1024 float4s, 2 per thread
#pragma unroll
        for (int i = 0; i < 2; ++i) {
            int q  = i * 512 + tid;       // 0..1023
            int s  = q >> 4;              // 0..63
            int kk = (q & 15) << 2;       // 0..60 step 4
            float4 v = make_float4(0.f, 0.f, 0.f, 0.f);
            if (kt + kk < K_DIM)          // K_DIM % 4 == 0, so full float4 ok
                v = *(const float4*)(x + (size_t)s * K_DIM + kt + kk);
            xs[(kk + 0) * XS_STRIDE + s] = v.x;
            xs[(kk + 1) * XS_STRIDE + s] = v.y;
            xs[(kk + 2) * XS_STRIDE + s] = v.z;
            xs[(kk + 3) * XS_STRIDE + s] = v.w;
        }
        __syncthreads();

        const float* wrow = Wi + (size_t)kt * NG + gbase;  // wave-uniform
        if (kt + TK <= K_DIM) {
#pragma unroll 4
            for (int k = 0; k < TK; ++k) {
                float xv = xs[k * XS_STRIDE + lane];
                const float* wr = wrow + (size_t)k * NG;
                float w[25];
#pragma unroll
                for (int j = 0; j < 25; ++j) w[j] = wr[j];   // uniform -> s_load
#pragma unroll
                for (int j = 0; j < 25; ++j) acc[j] = fmaf(w[j], xv, acc[j]);
            }
        } else {
            int rem = K_DIM - kt;
            for (int k = 0; k < rem; ++k) {
                float xv = xs[k * XS_STRIDE + lane];
                const float* wr = wrow + (size_t)k * NG;
#pragma unroll
                for (int j = 0; j < 25; ++j) acc[j] = fmaf(wr[j], xv, acc[j]);
            }
        }
    }
    // partial[b][g][s]: stores coalesced across lanes (s contiguous)
    float* pout = partial + (size_t)blockIdx.x * CELLS + (size_t)gbase * NS + lane;
#pragma unroll
    for (int j = 0; j < 25; ++j) pout[j * NS] = acc[j];
}

__global__ __launch_bounds__(256) void k2_reduce(
    const float* __restrict__ partial, const float* __restrict__ bi,
    const float* __restrict__ bh, float* __restrict__ gates)
{
    __shared__ float red[256];
    const int tid   = threadIdx.x;
    const int lane  = tid & 63;
    const int slice = tid >> 6;                 // 0..3, each sums 128 b's
    const int cell  = blockIdx.x * 64 + lane;   // = g*64 + s

    float sum = 0.f;
#pragma unroll 8
    for (int b = slice * 128; b < (slice + 1) * 128; ++b)
        sum += partial[(size_t)b * CELLS + cell];
    red[tid] = sum;
    __syncthreads();
    if (slice == 0) {
        float tot = red[lane] + red[64 + lane] + red[128 + lane] + red[192 + lane];
        int g = cell >> 6;
        int s = cell & 63;
        gates[s * NG + g] = tot + bi[g] + bh[g];  // gates[s][g]
    }
}

__global__ __launch_bounds__(256) void k3_lstm(
    const float* __restrict__ gates, const float* __restrict__ Wh,
    float* __restrict__ out)
{
    __shared__ float h_lds[64];
    __shared__ float act_lds[NG];
    const int g = threadIdx.x;   // gate index, active < 200

    float wh[50];
    if (g < NG) {
#pragma unroll
        for (int j = 0; j < 50; ++j) wh[j] = Wh[j * NG + g];  // coalesced column
    }
    if (g < 64) h_lds[g] = 0.f;
    float c = 0.f, h = 0.f;
    __syncthreads();

    for (int s = 0; s < 64; ++s) {
        if (g < NG) {
            float a0 = gates[s * NG + g];
            float a1 = 0.f;
#pragma unroll
            for (int jj = 0; jj < 50; jj += 2) {
                float2 h2 = *(const float2*)(h_lds + jj);  // broadcast b64
                a0 = fmaf(h2.x, wh[jj],     a0);
                a1 = fmaf(h2.y, wh[jj + 1], a1);
            }
            float z = a0 + a1;
            // sigmoid and tanh from one exp
            float e   = __expf(-z);
            float sig = 1.f / (1.f + e);
            float e2  = e * e;                       // e^{-2z}
            float th  = (1.f - e2) / (1.f + e2);
            act_lds[g] = ((g / 50) == 2) ? th : sig; // quarter 2 = cell gate
        }
        __syncthreads();
        if (g < 50) {
            float iv = act_lds[g];
            float fv = act_lds[50 + g];
            float gv = act_lds[100 + g];
            float ov = act_lds[150 + g];
            c = fmaf(fv, c, iv * gv);
            float e2c = __expf(-2.f * c);
            h = ov * (1.f - e2c) / (1.f + e2c);
            h_lds[g] = h;
        }
        __syncthreads();
    }
    if (g < 50) out[g] = h;
}

extern "C" void kernel_launch(void* const* d_in, const int* in_sizes, int n_in,
                              void* d_out, int out_size, void* d_ws, size_t ws_size,
                              hipStream_t stream)
{
    const float* x  = (const float*)d_in[0];
    const float* Wi = (const float*)d_in[1];
    const float* bi = (const float*)d_in[2];
    const float* Wh = (const float*)d_in[3];
    const float* bh = (const float*)d_in[4];
    float* out = (float*)d_out;

    float* partial = (float*)d_ws;                         // 512*12800 f32 = 26.2 MB
    float* gates   = partial + (size_t)NBLK * CELLS;       // 12800 f32

    k1_gemm_partial<<<NBLK, 512, 0, stream>>>(x, Wi, partial);
    k2_reduce<<<CELLS / 64, 256, 0, stream>>>(partial, bi, bh, gates);
    k3_lstm<<<1, 256, 0, stream>>>(gates, Wh, out);
}

// Round 2
// 229.402 us; speedup vs baseline: 1.2438x; 1.2438x over previous
//
#include <hip/hip_runtime.h>
#include <hip/hip_bf16.h>

// LSTM: SEQ=64, IN=100000, H=50 (4H=200 gates)
// x[64,100000] f32, Wi[100000,200] f32, bi[200], Wh[50,200], bh[200] -> h[50]
//
// K1: split-K GEMM C[64,200] = x @ Wi. Wi tile LDS-staged with coalesced
//     float4 loads + register prefetch (double-buffer without 2x LDS).
// K2: reduce 256 partials + bi + bh -> gates[s][g]
// K3: 64-step recurrence, single block.

#define K_DIM 100000
#define NG 200
#define NS 64
#define TK 32                    // k-rows per tile; 100000 % 32 == 0
#define NBLK 256
#define KSTRIDE (NBLK * TK)      // 8192
#define CELLS (NS * NG)          // 12800
#define XS_STRIDE 65             // (k*65+lane)%32 -> 2-way bank aliasing (free)

__global__ __launch_bounds__(512) void k1_gemm_partial(
    const float* __restrict__ x, const float* __restrict__ Wi,
    float* __restrict__ partial)
{
    __shared__ float4 ws4[TK * 50];         // 25600 B: Wi tile, [k][float4-col]
    __shared__ float  xs[TK * XS_STRIDE];   // 8320 B:  x tile, [k][s]

    const int tid  = threadIdx.x;
    const int lane = tid & 63;              // = s row in compute phase
    const int wave = tid >> 6;              // owns float4-cols {wave, wave+8, ...}

    // staging indices for x: 512 float4s, one per thread
    const int sx = tid >> 3;                // s row 0..63
    const int kq = (tid & 7) << 2;          // k offset 0,4,..,28
    const float4* wi4 = (const float4*)Wi;

    float acc[28];
#pragma unroll
    for (int j = 0; j < 28; ++j) acc[j] = 0.f;

    int kt = blockIdx.x * TK;

    // ---- prefetch first tile into registers (coalesced) ----
    float4 w0, w1, w2, w3 = make_float4(0.f, 0.f, 0.f, 0.f), xr;
    {
        const float4* wt = wi4 + (size_t)kt * 50;
        w0 = wt[tid];
        w1 = wt[tid + 512];
        w2 = wt[tid + 1024];
        if (tid < 64) w3 = wt[tid + 1536];
        xr = *(const float4*)(x + (size_t)sx * K_DIM + kt + kq);
    }

    for (; kt < K_DIM; kt += KSTRIDE) {
        __syncthreads();                    // previous tile's readers done
        // registers -> LDS (implicit vmcnt wait here)
        ws4[tid]        = w0;
        ws4[tid + 512]  = w1;
        ws4[tid + 1024] = w2;
        if (tid < 64) ws4[tid + 1536] = w3;
        xs[(kq + 0) * XS_STRIDE + sx] = xr.x;
        xs[(kq + 1) * XS_STRIDE + sx] = xr.y;
        xs[(kq + 2) * XS_STRIDE + sx] = xr.z;
        xs[(kq + 3) * XS_STRIDE + sx] = xr.w;
        __syncthreads();

        // ---- issue next tile's loads; latency overlaps compute below ----
        int ktn = kt + KSTRIDE;
        if (ktn < K_DIM) {
            const float4* wt = wi4 + (size_t)ktn * 50;
            w0 = wt[tid];
            w1 = wt[tid + 512];
            w2 = wt[tid + 1024];
            if (tid < 64) w3 = wt[tid + 1536];
            xr = *(const float4*)(x + (size_t)sx * K_DIM + ktn + kq);
        }

        // ---- compute: per k, 1 xs read + 6(+1) b128 broadcasts + 24-28 FMA ----
#pragma unroll 2
        for (int k = 0; k < TK; ++k) {
            float xv = xs[k * XS_STRIDE + lane];
#pragma unroll
            for (int j = 0; j < 6; ++j) {
                float4 wv = ws4[k * 50 + wave + 8 * j];
                acc[4*j+0] = fmaf(wv.x, xv, acc[4*j+0]);
                acc[4*j+1] = fmaf(wv.y, xv, acc[4*j+1]);
                acc[4*j+2] = fmaf(wv.z, xv, acc[4*j+2]);
                acc[4*j+3] = fmaf(wv.w, xv, acc[4*j+3]);
            }
            if (wave < 2) {                 // waves 0,1 own a 7th column
                float4 wv = ws4[k * 50 + wave + 48];
                acc[24] = fmaf(wv.x, xv, acc[24]);
                acc[25] = fmaf(wv.y, xv, acc[25]);
                acc[26] = fmaf(wv.z, xv, acc[26]);
                acc[27] = fmaf(wv.w, xv, acc[27]);
            }
        }
    }

    // partial[b][g][s]: lane-coalesced stores
    float* pout = partial + (size_t)blockIdx.x * CELLS + lane;
#pragma unroll
    for (int j = 0; j < 6; ++j) {
        int c = wave + 8 * j;
#pragma unroll
        for (int jj = 0; jj < 4; ++jj)
            pout[(4 * c + jj) * NS] = acc[4*j + jj];
    }
    if (wave < 2) {
        int c = wave + 48;
#pragma unroll
        for (int jj = 0; jj < 4; ++jj)
            pout[(4 * c + jj) * NS] = acc[24 + jj];
    }
}

__global__ __launch_bounds__(256) void k2_reduce(
    const float* __restrict__ partial, const float* __restrict__ bi,
    const float* __restrict__ bh, float* __restrict__ gates)
{
    __shared__ float red[256];
    const int tid   = threadIdx.x;
    const int lane  = tid & 63;             // = s
    const int slice = tid >> 6;             // 0..3, each sums 64 b's
    const int g     = blockIdx.x;           // 0..199
    const int cell  = g * NS + lane;

    float sum = 0.f;
#pragma unroll 8
    for (int b = slice * 64; b < (slice + 1) * 64; ++b)
        sum += partial[(size_t)b * CELLS + cell];
    red[tid] = sum;
    __syncthreads();
    if (slice == 0) {
        float tot = red[lane] + red[64 + lane] + red[128 + lane] + red[192 + lane];
        gates[lane * NG + g] = tot + bi[g] + bh[g];   // gates[s][g]
    }
}

__global__ __launch_bounds__(256) void k3_lstm(
    const float* __restrict__ gates, const float* __restrict__ Wh,
    float* __restrict__ out)
{
    __shared__ float h_lds[64];
    __shared__ float act_lds[NG];
    const int g = threadIdx.x;   // gate index, active < 200

    float wh[50];
    if (g < NG) {
#pragma unroll
        for (int j = 0; j < 50; ++j) wh[j] = Wh[j * NG + g];  // coalesced column
    }
    if (g < 64) h_lds[g] = 0.f;
    float c = 0.f, h = 0.f;
    __syncthreads();

    for (int s = 0; s < 64; ++s) {
        if (g < NG) {
            float a0 = gates[s * NG + g];
            float a1 = 0.f;
#pragma unroll
            for (int jj = 0; jj < 50; jj += 2) {
                float2 h2 = *(const float2*)(h_lds + jj);  // LDS broadcast
                a0 = fmaf(h2.x, wh[jj],     a0);
                a1 = fmaf(h2.y, wh[jj + 1], a1);
            }
            float z = a0 + a1;
            float e   = __expf(-z);
            float sig = 1.f / (1.f + e);
            float e2  = e * e;                        // e^{-2z}
            float th  = (1.f - e2) / (1.f + e2);
            act_lds[g] = ((g / 50) == 2) ? th : sig;  // quarter 2 = cell gate
        }
        __syncthreads();
        if (g < 50) {
            float iv = act_lds[g];
            float fv = act_lds[50 + g];
            float gv = act_lds[100 + g];
            float ov = act_lds[150 + g];
            c = fmaf(fv, c, iv * gv);
            float e2c = __expf(-2.f * c);
            h = ov * (1.f - e2c) / (1.f + e2c);
            h_lds[g] = h;
        }
        __syncthreads();
    }
    if (g < 50) out[g] = h;
}

extern "C" void kernel_launch(void* const* d_in, const int* in_sizes, int n_in,
                              void* d_out, int out_size, void* d_ws, size_t ws_size,
                              hipStream_t stream)
{
    const float* x  = (const float*)d_in[0];
    const float* Wi = (const float*)d_in[1];
    const float* bi = (const float*)d_in[2];
    const float* Wh = (const float*)d_in[3];
    const float* bh = (const float*)d_in[4];
    float* out = (float*)d_out;

    float* partial = (float*)d_ws;                    // 256*12800 f32 = 13.1 MB
    float* gates   = partial + (size_t)NBLK * CELLS;  // 12800 f32

    k1_gemm_partial<<<NBLK, 512, 0, stream>>>(x, Wi, partial);
    k2_reduce<<<NG, 256, 0, stream>>>(partial, bi, bh, gates);
    k3_lstm<<<1, 256, 0, stream>>>(gates, Wh, out);
}

// Round 3
// 205.186 us; speedup vs baseline: 1.3906x; 1.1180x over previous
//
#include <hip/hip_runtime.h>
#include <hip/hip_bf16.h>

// LSTM: SEQ=64, IN=100000, H=50 (4H=200 gates)
// x[64,100000] f32, Wi[100000,200] f32, bi[200], Wh[50,200], bh[200] -> h[50]
//
// K1: split-K GEMM C[64,200] = x @ Wi.
//     Layout: lane = float4 g-col (50 active), wave = 8 s-rows.
//     Per wave-k-step: 1 distinct b128 (W) + 2 broadcast b128 (x) + 32 FMA.
//     Partial stored [b][s][g] (coalesced f4).
// K2: reduce 512 partials + bi + bh -> gates[s*200+g]
// K3: 64-step recurrence, single block, gates staged in LDS (no global in loop).

#define K_DIM 100000
#define NG 200
#define NS 64
#define TK 32                    // k-rows per tile; 100000 % 32 == 0
#define NBLK 512
#define KSTRIDE (NBLK * TK)      // 16384
#define CELLS (NS * NG)          // 12800
#define XS_STRIDE 68             // 272B: 16B-aligned rows, 4-way store conflict only

__global__ __launch_bounds__(512, 4) void k1_gemm_partial(
    const float* __restrict__ x, const float* __restrict__ Wi,
    float* __restrict__ partial)
{
    __shared__ float4 ws4[TK * 50];          // 25600 B: Wi tile, [k][f4-col]
    __shared__ float  xs[TK * XS_STRIDE];    // 8704 B:  x tile, [k][s]

    const int tid  = threadIdx.x;
    const int lane = tid & 63;               // f4 g-col, active if < 50
    const int wave = tid >> 6;               // 0..7, owns s rows 8w..8w+7
    const int s0   = wave * 8;

    // staging indices for x: 512 float4s, one per thread
    const int sx = tid >> 3;                 // s row 0..63
    const int kq = (tid & 7) << 2;           // k offset 0,4,..,28
    const float4* wi4 = (const float4*)Wi;

    float4 acc4[8];
#pragma unroll
    for (int j = 0; j < 8; ++j) acc4[j] = make_float4(0.f, 0.f, 0.f, 0.f);

    int kt = blockIdx.x * TK;

    // ---- prefetch first tile into registers (coalesced) ----
    float4 w0, w1, w2, w3 = make_float4(0.f, 0.f, 0.f, 0.f), xr;
    {
        const float4* wt = wi4 + (size_t)kt * 50;
        w0 = wt[tid];
        w1 = wt[tid + 512];
        w2 = wt[tid + 1024];
        if (tid < 64) w3 = wt[tid + 1536];
        xr = *(const float4*)(x + (size_t)sx * K_DIM + kt + kq);
    }

    for (; kt < K_DIM; kt += KSTRIDE) {
        __syncthreads();                     // previous tile's readers done
        ws4[tid]        = w0;
        ws4[tid + 512]  = w1;
        ws4[tid + 1024] = w2;
        if (tid < 64) ws4[tid + 1536] = w3;
        xs[(kq + 0) * XS_STRIDE + sx] = xr.x;
        xs[(kq + 1) * XS_STRIDE + sx] = xr.y;
        xs[(kq + 2) * XS_STRIDE + sx] = xr.z;
        xs[(kq + 3) * XS_STRIDE + sx] = xr.w;
        __syncthreads();

        // issue next tile's global loads; latency hides behind compute below
        int ktn = kt + KSTRIDE;
        if (ktn < K_DIM) {
            const float4* wt = wi4 + (size_t)ktn * 50;
            w0 = wt[tid];
            w1 = wt[tid + 512];
            w2 = wt[tid + 1024];
            if (tid < 64) w3 = wt[tid + 1536];
            xr = *(const float4*)(x + (size_t)sx * K_DIM + ktn + kq);
        }

        if (lane < 50) {
#pragma unroll 4
            for (int k = 0; k < TK; ++k) {
                float4 wv = ws4[k * 50 + lane];                    // distinct b128
                const float4* xrow = (const float4*)(xs + k * XS_STRIDE + s0);
                float4 xa = xrow[0];                               // broadcast b128
                float4 xb = xrow[1];                               // broadcast b128
                acc4[0].x = fmaf(wv.x, xa.x, acc4[0].x);
                acc4[0].y = fmaf(wv.y, xa.x, acc4[0].y);
                acc4[0].z = fmaf(wv.z, xa.x, acc4[0].z);
                acc4[0].w = fmaf(wv.w, xa.x, acc4[0].w);
                acc4[1].x = fmaf(wv.x, xa.y, acc4[1].x);
                acc4[1].y = fmaf(wv.y, xa.y, acc4[1].y);
                acc4[1].z = fmaf(wv.z, xa.y, acc4[1].z);
                acc4[1].w = fmaf(wv.w, xa.y, acc4[1].w);
                acc4[2].x = fmaf(wv.x, xa.z, acc4[2].x);
                acc4[2].y = fmaf(wv.y, xa.z, acc4[2].y);
                acc4[2].z = fmaf(wv.z, xa.z, acc4[2].z);
                acc4[2].w = fmaf(wv.w, xa.z, acc4[2].w);
                acc4[3].x = fmaf(wv.x, xa.w, acc4[3].x);
                acc4[3].y = fmaf(wv.y, xa.w, acc4[3].y);
                acc4[3].z = fmaf(wv.z, xa.w, acc4[3].z);
                acc4[3].w = fmaf(wv.w, xa.w, acc4[3].w);
                acc4[4].x = fmaf(wv.x, xb.x, acc4[4].x);
                acc4[4].y = fmaf(wv.y, xb.x, acc4[4].y);
                acc4[4].z = fmaf(wv.z, xb.x, acc4[4].z);
                acc4[4].w = fmaf(wv.w, xb.x, acc4[4].w);
                acc4[5].x = fmaf(wv.x, xb.y, acc4[5].x);
                acc4[5].y = fmaf(wv.y, xb.y, acc4[5].y);
                acc4[5].z = fmaf(wv.z, xb.y, acc4[5].z);
                acc4[5].w = fmaf(wv.w, xb.y, acc4[5].w);
                acc4[6].x = fmaf(wv.x, xb.z, acc4[6].x);
                acc4[6].y = fmaf(wv.y, xb.z, acc4[6].y);
                acc4[6].z = fmaf(wv.z, xb.z, acc4[6].z);
                acc4[6].w = fmaf(wv.w, xb.z, acc4[6].w);
                acc4[7].x = fmaf(wv.x, xb.w, acc4[7].x);
                acc4[7].y = fmaf(wv.y, xb.w, acc4[7].y);
                acc4[7].z = fmaf(wv.z, xb.w, acc4[7].z);
                acc4[7].w = fmaf(wv.w, xb.w, acc4[7].w);
            }
        }
    }

    // partial[b][s][g]: f4 stores, 50 lanes x 16B contiguous = coalesced
    if (lane < 50) {
        float4* pout = (float4*)(partial + (size_t)blockIdx.x * CELLS) + lane;
#pragma unroll
        for (int si = 0; si < 8; ++si)
            pout[(s0 + si) * 50] = acc4[si];
    }
}

__global__ __launch_bounds__(256) void k2_reduce(
    const float* __restrict__ partial, const float* __restrict__ bi,
    const float* __restrict__ bh, float* __restrict__ gates)
{
    __shared__ float red[256];
    const int tid   = threadIdx.x;
    const int lane  = tid & 63;
    const int slice = tid >> 6;                 // 0..3, each sums 128 b's
    const int cell  = blockIdx.x * 64 + lane;   // = s*200 + g

    float sum = 0.f;
#pragma unroll 8
    for (int b = slice * 128; b < (slice + 1) * 128; ++b)
        sum += partial[(size_t)b * CELLS + cell];
    red[tid] = sum;
    __syncthreads();
    if (slice == 0) {
        float tot = red[lane] + red[64 + lane] + red[128 + lane] + red[192 + lane];
        int g = cell % NG;
        gates[cell] = tot + bi[g] + bh[g];
    }
}

__global__ __launch_bounds__(256) void k3_lstm(
    const float* __restrict__ gates, const float* __restrict__ Wh,
    float* __restrict__ out)
{
    __shared__ float gz[CELLS];     // 51.2 KB: all gate pre-activations
    __shared__ float h_lds[64];
    __shared__ float act_lds[NG];
    const int g = threadIdx.x;      // gate index, active < 200

    // stage gates -> LDS (coalesced); step loop then touches no global memory
    for (int i = g; i < CELLS; i += 256) gz[i] = gates[i];

    float wh[50];
    if (g < NG) {
#pragma unroll
        for (int j = 0; j < 50; ++j) wh[j] = Wh[j * NG + g];  // coalesced column
    }
    if (g < 64) h_lds[g] = 0.f;
    float c = 0.f, h = 0.f;
    const bool is_cell_gate = (g >= 100 && g < 150);
    __syncthreads();

    for (int s = 0; s < 64; ++s) {
        if (g < NG) {
            float a0 = gz[s * NG + g];
            float a1 = 0.f;
#pragma unroll
            for (int jj = 0; jj < 50; jj += 2) {
                float2 h2 = *(const float2*)(h_lds + jj);  // LDS broadcast
                a0 = fmaf(h2.x, wh[jj],     a0);
                a1 = fmaf(h2.y, wh[jj + 1], a1);
            }
            float z = a0 + a1;
            float e   = __expf(-z);
            float sig = 1.f / (1.f + e);
            float e2  = e * e;                        // e^{-2z}
            float th  = (1.f - e2) / (1.f + e2);
            act_lds[g] = is_cell_gate ? th : sig;
        }
        __syncthreads();
        if (g < 50) {
            float iv = act_lds[g];
            float fv = act_lds[50 + g];
            float gv = act_lds[100 + g];
            float ov = act_lds[150 + g];
            c = fmaf(fv, c, iv * gv);
            float e2c = __expf(-2.f * c);
            h = ov * (1.f - e2c) / (1.f + e2c);
            h_lds[g] = h;
        }
        __syncthreads();
    }
    if (g < 50) out[g] = h;
}

extern "C" void kernel_launch(void* const* d_in, const int* in_sizes, int n_in,
                              void* d_out, int out_size, void* d_ws, size_t ws_size,
                              hipStream_t stream)
{
    const float* x  = (const float*)d_in[0];
    const float* Wi = (const float*)d_in[1];
    const float* bi = (const float*)d_in[2];
    const float* Wh = (const float*)d_in[3];
    const float* bh = (const float*)d_in[4];
    float* out = (float*)d_out;

    float* partial = (float*)d_ws;                    // 512*12800 f32 = 26.2 MB
    float* gates   = partial + (size_t)NBLK * CELLS;  // 12800 f32

    k1_gemm_partial<<<NBLK, 512, 0, stream>>>(x, Wi, partial);
    k2_reduce<<<CELLS / 64, 256, 0, stream>>>(partial, bi, bh, gates);
    k3_lstm<<<1, 256, 0, stream>>>(gates, Wh, out);
}